// Round 4
// baseline (834.268 us; speedup 1.0000x reference)
//
#include <hip/hip_runtime.h>
#include <math.h>

#define B 64
#define N 8192
#define D 128
#define H 512
#define NHEAD 4
#define GDW 390
#define GDR 134
#define KL 1152   /* 640 + 512 */
#define EPSF 1e-10f

typedef float f4 __attribute__((ext_vector_type(4)));

__device__ __forceinline__ float softplusf(float x) {
    return x > 20.f ? x : log1pf(expf(x));
}
__device__ __forceinline__ float sigmoidf(float x) {
    return 1.f / (1.f + expf(-x));
}

// ---------------------------------------------------------------- controller GEMM
// concat(x, prev_y, prev_read, h0) gathered inline into LDS (prep_xt fused away).
__global__ __launch_bounds__(256) void controller(const float* __restrict__ x,
        const float* __restrict__ py, const float* __restrict__ pr,
        const float* __restrict__ h0,
        const float* __restrict__ W_ih, const float* __restrict__ W_hh,
        const float* __restrict__ b_ih, const float* __restrict__ b_hh,
        float* __restrict__ gatesT) {
    __shared__ float xs[64 * 64];
    int tid = threadIdx.x;
    int lane = tid & 63;
    int wave = tid >> 6;
    int j0 = blockIdx.x * 16 + wave * 4;
    float acc[4] = {0.f, 0.f, 0.f, 0.f};
    for (int k0 = 0; k0 < KL; k0 += 64) {
        __syncthreads();
        #pragma unroll
        for (int i = 0; i < 16; i++) {
            int idx = k0 * 64 + tid + i * 256;
            int k = idx >> 6, b = idx & 63;
            float v;
            if (k < 64)       v = x[b * 64 + k];
            else if (k < 128) v = py[b * 64 + (k - 64)];
            else if (k < 640) v = pr[b * 512 + (k - 128)];
            else              v = h0[b * 512 + (k - 640)];
            xs[tid + i * 256] = v;
        }
        __syncthreads();
        const float* wp[4];
        #pragma unroll
        for (int jj = 0; jj < 4; jj++) {
            int j = j0 + jj;
            wp[jj] = (k0 < 640) ? (W_ih + j * 640 + k0) : (W_hh + j * 512 + (k0 - 640));
        }
        #pragma unroll 4
        for (int k = 0; k < 64; k++) {
            float xv = xs[k * 64 + lane];
            #pragma unroll
            for (int jj = 0; jj < 4; jj++) acc[jj] = fmaf(wp[jj][k], xv, acc[jj]);
        }
    }
    #pragma unroll
    for (int jj = 0; jj < 4; jj++) {
        int j = j0 + jj;
        gatesT[j * 64 + lane] = acc[jj] + b_ih[j] + b_hh[j];
    }
}

// ---------------------------------------------------------------- LSTM cell
__global__ void lstm_cell(const float* __restrict__ gatesT, const float* __restrict__ c0,
                          float* __restrict__ h_out, float* __restrict__ c_out,
                          float* __restrict__ HT) {
    int tid = blockIdx.x * 256 + threadIdx.x;  // 32768
    int b = tid >> 9, u = tid & 511;
    float gi = gatesT[u * 64 + b];
    float gf = gatesT[(512 + u) * 64 + b];
    float gg = gatesT[(1024 + u) * 64 + b];
    float go = gatesT[(1536 + u) * 64 + b];
    float c = sigmoidf(gf) * c0[b * 512 + u] + sigmoidf(gi) * tanhf(gg);
    float h = sigmoidf(go) * tanhf(c);
    c_out[b * 512 + u] = c;
    h_out[b * 512 + u] = h;
    HT[u * 64 + b] = h;
}

// ---------------------------------------------------------------- head projections
__global__ __launch_bounds__(256) void head_proj(const float* __restrict__ HT,
        const float* __restrict__ W_w, const float* __restrict__ W_r,
        const float* __restrict__ b_w, const float* __restrict__ b_r,
        float* __restrict__ o_w, float* __restrict__ o_r) {
    __shared__ float xs[64 * 64];
    int tid = threadIdx.x;
    int lane = tid & 63;
    int wave = tid >> 6;
    int j0 = blockIdx.x * 16 + wave * 4;
    float acc[4] = {0.f, 0.f, 0.f, 0.f};
    const float* wp[4];
    #pragma unroll
    for (int jj = 0; jj < 4; jj++) {
        int j = j0 + jj;
        wp[jj] = (j < 1560) ? (W_w + j * 512) : (W_r + (j - 1560) * 512);
    }
    for (int k0 = 0; k0 < 512; k0 += 64) {
        __syncthreads();
        #pragma unroll
        for (int i = 0; i < 16; i++) xs[tid + i * 256] = HT[k0 * 64 + tid + i * 256];
        __syncthreads();
        #pragma unroll 4
        for (int k = 0; k < 64; k++) {
            float xv = xs[k * 64 + lane];
            #pragma unroll
            for (int jj = 0; jj < 4; jj++) acc[jj] = fmaf(wp[jj][k0 + k], xv, acc[jj]);
        }
    }
    #pragma unroll
    for (int jj = 0; jj < 4; jj++) {
        int j = j0 + jj;
        if (j < 1560) o_w[lane * 1560 + j] = acc[jj] + b_w[j];
        else          o_r[lane * 536 + (j - 1560)] = acc[jj] + b_r[j - 1560];
    }
}

// ---------------------------------------------------------------- head params (+ zero r workspace)
__global__ __launch_bounds__(128) void head_params(const float* __restrict__ o_w,
        const float* __restrict__ o_r, float* __restrict__ knw, float* __restrict__ knr,
        float* __restrict__ pw, float* __restrict__ prd, float* __restrict__ rzero) {
    __shared__ float red[2];
    int id = blockIdx.x;
    if (id < 256) rzero[id * 128 + threadIdx.x] = 0.f;   // fused zero of r workspace (32768)
    bool isw = id < 256;
    int bh = isw ? id : id - 256;
    const float* o = isw ? (o_w + (bh >> 2) * 1560 + (bh & 3) * GDW)
                         : (o_r + (bh >> 2) * 536 + (bh & 3) * GDR);
    float* kn = (isw ? knw : knr) + bh * 128;
    float* pp = (isw ? pw : prd) + bh * 6;
    int t = threadIdx.x;
    float kv = o[t];
    float ss = kv * kv;
    #pragma unroll
    for (int m = 1; m < 64; m <<= 1) ss += __shfl_xor(ss, m);
    if ((t & 63) == 0) red[t >> 6] = ss;
    __syncthreads();
    float norm = sqrtf(red[0] + red[1]);
    kn[t] = kv / (norm + EPSF);
    if (t == 0) {
        float beta = softplusf(o[128]);
        float g = sigmoidf(o[129]);
        float s0 = softplusf(o[130]), s1 = softplusf(o[131]), s2 = softplusf(o[132]);
        float mx = fmaxf(s0, fmaxf(s1, s2));
        float e0 = expf(s0 - mx), e1 = expf(s1 - mx), e2 = expf(s2 - mx);
        float inv = 1.f / (e0 + e1 + e2);
        float gamma = 1.f + softplusf(o[133]);
        pp[0] = beta; pp[1] = g; pp[2] = e0 * inv; pp[3] = e1 * inv; pp[4] = e2 * inv; pp[5] = gamma;
    }
}

// ---------------------------------------------------------------- sim (write heads)
// Transposed layout: 16 lanes per row, 4-level packed reduce. Plain (cached) loads:
// mem_in must stay L3-resident for mem_update's second pass.
__global__ __launch_bounds__(256) void sim_write(const float* __restrict__ mem,
        const float* __restrict__ knw, float* __restrict__ sim) {
    int t = threadIdx.x;
    int lane = t & 63;
    int wv = t >> 6;
    int j = lane & 15;
    int u = lane >> 4;
    int b = blockIdx.x >> 7;
    int nb = (blockIdx.x & 127) * 64 + wv * 16 + u;
    f4 k[4][2];
    #pragma unroll
    for (int h = 0; h < 4; h++) {
        #pragma unroll
        for (int s = 0; s < 2; s++)
            k[h][s] = *(const f4*)(knw + (b * 4 + h) * 128 + s * 64 + j * 4);
    }
    #pragma unroll
    for (int it = 0; it < 4; it++) {
        int n = nb + it * 4;
        size_t base = ((size_t)b * N + n) * D + j * 4;
        const f4 m0 = *(const f4*)(mem + base);
        const f4 m1 = *(const f4*)(mem + base + 64);
        float s0 = m0.x*k[0][0].x + m0.y*k[0][0].y + m0.z*k[0][0].z + m0.w*k[0][0].w
                 + m1.x*k[0][1].x + m1.y*k[0][1].y + m1.z*k[0][1].z + m1.w*k[0][1].w;
        float s1 = m0.x*k[1][0].x + m0.y*k[1][0].y + m0.z*k[1][0].z + m0.w*k[1][0].w
                 + m1.x*k[1][1].x + m1.y*k[1][1].y + m1.z*k[1][1].z + m1.w*k[1][1].w;
        float s2 = m0.x*k[2][0].x + m0.y*k[2][0].y + m0.z*k[2][0].z + m0.w*k[2][0].w
                 + m1.x*k[2][1].x + m1.y*k[2][1].y + m1.z*k[2][1].z + m1.w*k[2][1].w;
        float s3 = m0.x*k[3][0].x + m0.y*k[3][0].y + m0.z*k[3][0].z + m0.w*k[3][0].w
                 + m1.x*k[3][1].x + m1.y*k[3][1].y + m1.z*k[3][1].z + m1.w*k[3][1].w;
        float nn = m0.x*m0.x + m0.y*m0.y + m0.z*m0.z + m0.w*m0.w
                 + m1.x*m1.x + m1.y*m1.y + m1.z*m1.z + m1.w*m1.w;
        s0 += __shfl_xor(s0, 1); s1 += __shfl_xor(s1, 1);
        s2 += __shfl_xor(s2, 1); s3 += __shfl_xor(s3, 1); nn += __shfl_xor(nn, 1);
        float p01 = (j & 1) ? s1 : s0;
        float p23 = (j & 1) ? s3 : s2;
        p01 += __shfl_xor(p01, 2); p23 += __shfl_xor(p23, 2); nn += __shfl_xor(nn, 2);
        float q = (j & 2) ? p23 : p01;
        q += __shfl_xor(q, 4);  nn += __shfl_xor(nn, 4);
        q += __shfl_xor(q, 8);  nn += __shfl_xor(nn, 8);
        if (j < 4) sim[((size_t)(b * 4 + j)) * N + n] = q / (sqrtf(nn) + EPSF);
    }
}

// ---------------------------------------------------------------- address finalize
// 512 threads; pow result stored in pbuf, not recomputed.
__global__ __launch_bounds__(512) void addr_finalize(const float* __restrict__ sim,
        const float* __restrict__ prev_w, const float* __restrict__ par,
        float* __restrict__ w_out) {
    __shared__ float buf[N];    // 32KB
    __shared__ float pbuf[N];   // 32KB
    __shared__ float red[8];
    int bh = blockIdx.x;
    int t = threadIdx.x;
    const float* s = sim + (size_t)bh * N;
    const float* pw = prev_w + (size_t)bh * N;
    float beta = par[bh * 6 + 0], g = par[bh * 6 + 1];
    float s0 = par[bh * 6 + 2], s1 = par[bh * 6 + 3], s2 = par[bh * 6 + 4];
    float gamma = par[bh * 6 + 5];
    float mx = -INFINITY;
    for (int i = t; i < N; i += 512) {
        float e = beta * s[i];
        buf[i] = e;
        mx = fmaxf(mx, e);
    }
    #pragma unroll
    for (int m = 1; m < 64; m <<= 1) mx = fmaxf(mx, __shfl_xor(mx, m));
    if ((t & 63) == 0) red[t >> 6] = mx;
    __syncthreads();
    mx = red[0];
    #pragma unroll
    for (int kk = 1; kk < 8; kk++) mx = fmaxf(mx, red[kk]);
    float sum = 0.f;
    for (int i = t; i < N; i += 512) {
        float v = expf(buf[i] - mx);
        buf[i] = v;
        sum += v;
    }
    #pragma unroll
    for (int m = 1; m < 64; m <<= 1) sum += __shfl_xor(sum, m);
    __syncthreads();
    if ((t & 63) == 0) red[t >> 6] = sum;
    __syncthreads();
    sum = red[0] + red[1] + red[2] + red[3] + red[4] + red[5] + red[6] + red[7];
    float inv = 1.f / sum;
    for (int i = t; i < N; i += 512) buf[i] = g * (buf[i] * inv) + (1.f - g) * pw[i];
    __syncthreads();
    float psum = 0.f;
    for (int i = t; i < N; i += 512) {
        float wsv = s0 * buf[(i + N - 1) & (N - 1)] + s1 * buf[i] + s2 * buf[(i + 1) & (N - 1)];
        float pv = powf(wsv, gamma);
        pbuf[i] = pv;
        psum += pv;
    }
    #pragma unroll
    for (int m = 1; m < 64; m <<= 1) psum += __shfl_xor(psum, m);
    __syncthreads();
    if ((t & 63) == 0) red[t >> 6] = psum;
    __syncthreads();
    psum = red[0] + red[1] + red[2] + red[3] + red[4] + red[5] + red[6] + red[7];
    float rinv = 1.f / (psum + EPSF);
    for (int i = t; i < N; i += 512) w_out[(size_t)bh * N + i] = pbuf[i] * rinv;
}

// ---------------------------------------------------------------- memory update + read-head sim (fused)
// w_w staged through LDS; packed reduce; unrolled; plain cached loads/stores so
// mem_in hits L3 (written by sim_write's pass) and mem_o stays L3-resident for read_vec.
__global__ __launch_bounds__(256) void mem_update(const float* __restrict__ mem_in,
        const float* __restrict__ o_w, const float* __restrict__ w_w,
        const float* __restrict__ knr, float* __restrict__ mem_out,
        float* __restrict__ simr) {
    __shared__ float wlds[4][64];
    int t = threadIdx.x;
    int l = t & 31;
    int rg = t >> 5;
    int b = blockIdx.x >> 7;
    int n0 = (blockIdx.x & 127) * 64;
    {
        int h = t >> 6, idx = t & 63;
        wlds[h][idx] = w_w[((size_t)(b * 4 + h)) * N + n0 + idx];
    }
    f4 e[4], a[4], kr[4];
    #pragma unroll
    for (int h = 0; h < 4; h++) {
        const float* ob = o_w + b * 1560 + h * GDW;
        // offsets only 8B-aligned: scalar loads
        e[h].x = ob[134 + l * 4 + 0]; e[h].y = ob[134 + l * 4 + 1];
        e[h].z = ob[134 + l * 4 + 2]; e[h].w = ob[134 + l * 4 + 3];
        a[h].x = ob[262 + l * 4 + 0]; a[h].y = ob[262 + l * 4 + 1];
        a[h].z = ob[262 + l * 4 + 2]; a[h].w = ob[262 + l * 4 + 3];
        kr[h] = *(const f4*)(knr + (b * 4 + h) * 128 + l * 4);
    }
    __syncthreads();
    #pragma unroll
    for (int it = 0; it < 8; it++) {
        int n = n0 + it * 8 + rg;
        size_t base = ((size_t)b * N + n) * D + l * 4;
        f4 m = *(const f4*)(mem_in + base);
        #pragma unroll
        for (int h = 0; h < 4; h++) {
            float wv = wlds[h][it * 8 + rg];
            m.x = m.x * (1.f - wv * e[h].x) + wv * a[h].x;
            m.y = m.y * (1.f - wv * e[h].y) + wv * a[h].y;
            m.z = m.z * (1.f - wv * e[h].z) + wv * a[h].z;
            m.w = m.w * (1.f - wv * e[h].w) + wv * a[h].w;
        }
        *(f4*)(mem_out + base) = m;
        float s0 = m.x * kr[0].x + m.y * kr[0].y + m.z * kr[0].z + m.w * kr[0].w;
        float s1 = m.x * kr[1].x + m.y * kr[1].y + m.z * kr[1].z + m.w * kr[1].w;
        float s2 = m.x * kr[2].x + m.y * kr[2].y + m.z * kr[2].z + m.w * kr[2].w;
        float s3 = m.x * kr[3].x + m.y * kr[3].y + m.z * kr[3].z + m.w * kr[3].w;
        float nn = m.x * m.x + m.y * m.y + m.z * m.z + m.w * m.w;
        s0 += __shfl_xor(s0, 1); s1 += __shfl_xor(s1, 1);
        s2 += __shfl_xor(s2, 1); s3 += __shfl_xor(s3, 1); nn += __shfl_xor(nn, 1);
        float p01 = (l & 1) ? s1 : s0;
        float p23 = (l & 1) ? s3 : s2;
        p01 += __shfl_xor(p01, 2); p23 += __shfl_xor(p23, 2); nn += __shfl_xor(nn, 2);
        float q = (l & 2) ? p23 : p01;
        q += __shfl_xor(q, 4); nn += __shfl_xor(nn, 4);
        float z = (l & 4) ? nn : q;
        z += __shfl_xor(z, 8);
        z += __shfl_xor(z, 16);
        float nnv = __shfl_xor(z, 4);
        if (l < 4) simr[((size_t)(b * 4 + l)) * N + n] = z / (sqrtf(nnv) + EPSF);
    }
}

// ---------------------------------------------------------------- read vector
// w_r staged through LDS; stream loop unrolled x4; plain loads (mem_o should hit L3).
__global__ __launch_bounds__(256) void read_vec(const float* __restrict__ mem,
        const float* __restrict__ w_r, float* __restrict__ r) {
    __shared__ float lds[8 * 512];
    __shared__ float wlds[4][512];
    int t = threadIdx.x;
    int l = t & 31;
    int rg = t >> 5;
    int b = blockIdx.x >> 4;
    int n0 = (blockIdx.x & 15) * 512;
    for (int i = t; i < 2048; i += 256) {
        int h = i >> 9, idx = i & 511;
        wlds[h][idx] = w_r[((size_t)(b * 4 + h)) * N + n0 + idx];
    }
    __syncthreads();
    f4 acc[4];
    #pragma unroll
    for (int h = 0; h < 4; h++) acc[h] = (f4){0.f, 0.f, 0.f, 0.f};
    #pragma unroll 4
    for (int it = 0; it < 64; it++) {
        int nl = it * 8 + rg;
        const f4 m = *(const f4*)(mem + ((size_t)b * N + n0 + nl) * D + l * 4);
        #pragma unroll
        for (int h = 0; h < 4; h++) {
            float wv = wlds[h][nl];
            acc[h].x += wv * m.x;
            acc[h].y += wv * m.y;
            acc[h].z += wv * m.z;
            acc[h].w += wv * m.w;
        }
    }
    #pragma unroll
    for (int h = 0; h < 4; h++) *(f4*)(lds + rg * 512 + h * 128 + l * 4) = acc[h];
    __syncthreads();
    for (int o = t; o < 512; o += 256) {
        float sum = 0.f;
        #pragma unroll
        for (int g2 = 0; g2 < 8; g2++) sum += lds[g2 * 512 + o];
        atomicAdd(&r[b * 512 + o], sum);
    }
}

// ---------------------------------------------------------------- output
__global__ __launch_bounds__(64) void out_y(const float* __restrict__ h,
        const float* __restrict__ r, const float* __restrict__ W_out,
        const float* __restrict__ b_out, float* __restrict__ y) {
    int b = blockIdx.x >> 6;
    int j = blockIdx.x & 63;
    int l = threadIdx.x;
    float acc = 0.f;
    #pragma unroll
    for (int kk = 0; kk < 16; kk++) {
        int k = l + kk * 64;
        float x = (k < 512) ? h[b * 512 + k] : r[b * 512 + (k - 512)];
        acc = fmaf(W_out[j * 1024 + k], x, acc);
    }
    #pragma unroll
    for (int m = 1; m < 64; m <<= 1) acc += __shfl_xor(acc, m);
    if (l == 0) y[b * 64 + j] = tanhf(acc + b_out[j]);
}

extern "C" void kernel_launch(void* const* d_in, const int* in_sizes, int n_in,
                              void* d_out, int out_size, void* d_ws, size_t ws_size,
                              hipStream_t stream) {
    const float* x_input      = (const float*)d_in[0];
    const float* prev_y       = (const float*)d_in[1];
    const float* prev_read    = (const float*)d_in[2];
    const float* memory       = (const float*)d_in[3];
    const float* prev_w_read  = (const float*)d_in[4];
    const float* prev_w_write = (const float*)d_in[5];
    const float* h0           = (const float*)d_in[6];
    const float* c0           = (const float*)d_in[7];
    const float* W_ih         = (const float*)d_in[8];
    const float* W_hh         = (const float*)d_in[9];
    const float* b_ih         = (const float*)d_in[10];
    const float* b_hh         = (const float*)d_in[11];
    const float* W_rhead      = (const float*)d_in[12];
    const float* b_rhead      = (const float*)d_in[13];
    const float* W_whead      = (const float*)d_in[14];
    const float* b_whead      = (const float*)d_in[15];
    const float* W_out        = (const float*)d_in[16];
    const float* b_out        = (const float*)d_in[17];

    float* out = (float*)d_out;
    float* y_o   = out;                        // 4096
    float* mem_o = out + 4096;                 // 67108864
    float* h_o   = out + 4096 + 67108864;      // 32768
    float* c_o   = h_o + 32768;                // 32768
    float* wr_o  = c_o + 32768;                // 2097152
    float* ww_o  = wr_o + 2097152;             // 2097152

    float* ws     = (float*)d_ws;
    float* XT     = ws;                        // 73728 (unused now, layout kept)
    float* HT     = XT + 73728;                // 32768
    float* gatesT = HT + 32768;                // 131072
    float* o_w    = gatesT + 131072;           // 99840  (64*1560)
    float* o_r    = o_w + 99840;               // 34304  (64*536)
    float* knw    = o_r + 34304;               // 32768
    float* knr    = knw + 32768;               // 32768
    float* pw     = knr + 32768;               // 1536
    float* prd    = pw + 1536;                 // 1536
    float* sim_w  = prd + 1536;                // 2097152
    float* sim_r  = sim_w + 2097152;           // 2097152
    float* r_ws   = sim_r + 2097152;           // 32768

    controller<<<128, 256, 0, stream>>>(x_input, prev_y, prev_read, h0,
                                        W_ih, W_hh, b_ih, b_hh, gatesT);
    lstm_cell<<<128, 256, 0, stream>>>(gatesT, c0, h_o, c_o, HT);
    head_proj<<<131, 256, 0, stream>>>(HT, W_whead, W_rhead, b_whead, b_rhead, o_w, o_r);
    head_params<<<512, 128, 0, stream>>>(o_w, o_r, knw, knr, pw, prd, r_ws);
    sim_write<<<8192, 256, 0, stream>>>(memory, knw, sim_w);
    addr_finalize<<<256, 512, 0, stream>>>(sim_w, prev_w_write, pw, ww_o);
    mem_update<<<8192, 256, 0, stream>>>(memory, o_w, ww_o, knr, mem_o, sim_r);
    addr_finalize<<<256, 512, 0, stream>>>(sim_r, prev_w_read, prd, wr_o);
    read_vec<<<1024, 256, 0, stream>>>(mem_o, wr_o, r_ws);
    out_y<<<4096, 64, 0, stream>>>(h_o, r_ws, W_out, b_out, y_o);
}

// Round 5
// 746.752 us; speedup vs baseline: 1.1172x; 1.1172x over previous
//
#include <hip/hip_runtime.h>
#include <math.h>

#define B 64
#define N 8192
#define D 128
#define H 512
#define NHEAD 4
#define GDW 390
#define GDR 134
#define KL 1152   /* 640 + 512 */
#define EPSF 1e-10f

typedef float f4 __attribute__((ext_vector_type(4)));

__device__ __forceinline__ float softplusf(float x) {
    return x > 20.f ? x : log1pf(expf(x));
}
__device__ __forceinline__ float sigmoidf(float x) {
    return 1.f / (1.f + expf(-x));
}
__device__ __forceinline__ f4 ntload4(const float* p) {
    return __builtin_nontemporal_load((const f4*)p);
}
__device__ __forceinline__ void ntstore4(float* p, f4 v) {
    __builtin_nontemporal_store(v, (f4*)p);
}

// ---------------------------------------------------------------- prep XT
__global__ void prep_xt(const float* __restrict__ x, const float* __restrict__ py,
                        const float* __restrict__ pr, const float* __restrict__ h0,
                        float* __restrict__ XT) {
    int idx = blockIdx.x * 256 + threadIdx.x;
    if (idx >= KL * B) return;
    int k = idx >> 6, b = idx & 63;
    float v;
    if (k < 64)       v = x[b * 64 + k];
    else if (k < 128) v = py[b * 64 + (k - 64)];
    else if (k < 640) v = pr[b * 512 + (k - 128)];
    else              v = h0[b * 512 + (k - 640)];
    XT[idx] = v;
}

// ---------------------------------------------------------------- controller GEMM
__global__ __launch_bounds__(256) void controller(const float* __restrict__ XT,
        const float* __restrict__ W_ih, const float* __restrict__ W_hh,
        const float* __restrict__ b_ih, const float* __restrict__ b_hh,
        float* __restrict__ gatesT) {
    __shared__ float xs[64 * 64];
    int tid = threadIdx.x;
    int lane = tid & 63;
    int wave = tid >> 6;
    int j0 = blockIdx.x * 16 + wave * 4;
    float acc[4] = {0.f, 0.f, 0.f, 0.f};
    for (int k0 = 0; k0 < KL; k0 += 64) {
        __syncthreads();
        #pragma unroll
        for (int i = 0; i < 16; i++) xs[tid + i * 256] = XT[k0 * 64 + tid + i * 256];
        __syncthreads();
        const float* wp[4];
        #pragma unroll
        for (int jj = 0; jj < 4; jj++) {
            int j = j0 + jj;
            wp[jj] = (k0 < 640) ? (W_ih + j * 640 + k0) : (W_hh + j * 512 + (k0 - 640));
        }
        #pragma unroll 4
        for (int k = 0; k < 64; k++) {
            float xv = xs[k * 64 + lane];
            #pragma unroll
            for (int jj = 0; jj < 4; jj++) acc[jj] = fmaf(wp[jj][k], xv, acc[jj]);
        }
    }
    #pragma unroll
    for (int jj = 0; jj < 4; jj++) {
        int j = j0 + jj;
        gatesT[j * 64 + lane] = acc[jj] + b_ih[j] + b_hh[j];
    }
}

// ---------------------------------------------------------------- LSTM cell
__global__ void lstm_cell(const float* __restrict__ gatesT, const float* __restrict__ c0,
                          float* __restrict__ h_out, float* __restrict__ c_out,
                          float* __restrict__ HT) {
    int tid = blockIdx.x * 256 + threadIdx.x;  // 32768
    int b = tid >> 9, u = tid & 511;
    float gi = gatesT[u * 64 + b];
    float gf = gatesT[(512 + u) * 64 + b];
    float gg = gatesT[(1024 + u) * 64 + b];
    float go = gatesT[(1536 + u) * 64 + b];
    float c = sigmoidf(gf) * c0[b * 512 + u] + sigmoidf(gi) * tanhf(gg);
    float h = sigmoidf(go) * tanhf(c);
    c_out[b * 512 + u] = c;
    h_out[b * 512 + u] = h;
    HT[u * 64 + b] = h;
}

// ---------------------------------------------------------------- head projections
__global__ __launch_bounds__(256) void head_proj(const float* __restrict__ HT,
        const float* __restrict__ W_w, const float* __restrict__ W_r,
        const float* __restrict__ b_w, const float* __restrict__ b_r,
        float* __restrict__ o_w, float* __restrict__ o_r) {
    __shared__ float xs[64 * 64];
    int tid = threadIdx.x;
    int lane = tid & 63;
    int wave = tid >> 6;
    int j0 = blockIdx.x * 16 + wave * 4;
    float acc[4] = {0.f, 0.f, 0.f, 0.f};
    const float* wp[4];
    #pragma unroll
    for (int jj = 0; jj < 4; jj++) {
        int j = j0 + jj;
        wp[jj] = (j < 1560) ? (W_w + j * 512) : (W_r + (j - 1560) * 512);
    }
    for (int k0 = 0; k0 < 512; k0 += 64) {
        __syncthreads();
        #pragma unroll
        for (int i = 0; i < 16; i++) xs[tid + i * 256] = HT[k0 * 64 + tid + i * 256];
        __syncthreads();
        #pragma unroll 4
        for (int k = 0; k < 64; k++) {
            float xv = xs[k * 64 + lane];
            #pragma unroll
            for (int jj = 0; jj < 4; jj++) acc[jj] = fmaf(wp[jj][k0 + k], xv, acc[jj]);
        }
    }
    #pragma unroll
    for (int jj = 0; jj < 4; jj++) {
        int j = j0 + jj;
        if (j < 1560) o_w[lane * 1560 + j] = acc[jj] + b_w[j];
        else          o_r[lane * 536 + (j - 1560)] = acc[jj] + b_r[j - 1560];
    }
}

// ---------------------------------------------------------------- head params (+ zero r workspace)
__global__ __launch_bounds__(128) void head_params(const float* __restrict__ o_w,
        const float* __restrict__ o_r, float* __restrict__ knw, float* __restrict__ knr,
        float* __restrict__ pw, float* __restrict__ prd, float* __restrict__ rzero) {
    __shared__ float red[2];
    int id = blockIdx.x;
    if (id < 256) rzero[id * 128 + threadIdx.x] = 0.f;   // fused zero of r workspace (32768)
    bool isw = id < 256;
    int bh = isw ? id : id - 256;
    const float* o = isw ? (o_w + (bh >> 2) * 1560 + (bh & 3) * GDW)
                         : (o_r + (bh >> 2) * 536 + (bh & 3) * GDR);
    float* kn = (isw ? knw : knr) + bh * 128;
    float* pp = (isw ? pw : prd) + bh * 6;
    int t = threadIdx.x;
    float kv = o[t];
    float ss = kv * kv;
    #pragma unroll
    for (int m = 1; m < 64; m <<= 1) ss += __shfl_xor(ss, m);
    if ((t & 63) == 0) red[t >> 6] = ss;
    __syncthreads();
    float norm = sqrtf(red[0] + red[1]);
    kn[t] = kv / (norm + EPSF);
    if (t == 0) {
        float beta = softplusf(o[128]);
        float g = sigmoidf(o[129]);
        float s0 = softplusf(o[130]), s1 = softplusf(o[131]), s2 = softplusf(o[132]);
        float mx = fmaxf(s0, fmaxf(s1, s2));
        float e0 = expf(s0 - mx), e1 = expf(s1 - mx), e2 = expf(s2 - mx);
        float inv = 1.f / (e0 + e1 + e2);
        float gamma = 1.f + softplusf(o[133]);
        pp[0] = beta; pp[1] = g; pp[2] = e0 * inv; pp[3] = e1 * inv; pp[4] = e2 * inv; pp[5] = gamma;
    }
}

// ---------------------------------------------------------------- sim (write heads)
// Grid-stride: 2048 blocks, each handles 4 chunks of 64 rows (keys loaded ONCE).
// 16 lanes per row, 4-level packed reduce; mem reads nontemporal (skip L2, L3 is memory-side).
__global__ __launch_bounds__(256) void sim_write(const float* __restrict__ mem,
        const float* __restrict__ knw, float* __restrict__ sim) {
    int t = threadIdx.x;
    int lane = t & 63;
    int wv = t >> 6;
    int j = lane & 15;
    int u = lane >> 4;
    int b = blockIdx.x >> 5;
    int grp = blockIdx.x & 31;
    f4 k[4][2];
    #pragma unroll
    for (int h = 0; h < 4; h++) {
        #pragma unroll
        for (int s = 0; s < 2; s++)
            k[h][s] = *(const f4*)(knw + (b * 4 + h) * 128 + s * 64 + j * 4);
    }
    for (int cc = 0; cc < 4; cc++) {
        int nb = (grp * 4 + cc) * 64 + wv * 16 + u;
        #pragma unroll
        for (int it = 0; it < 4; it++) {
            int n = nb + it * 4;
            size_t base = ((size_t)b * N + n) * D + j * 4;
            const f4 m0 = ntload4(mem + base);
            const f4 m1 = ntload4(mem + base + 64);
            float s0 = m0.x*k[0][0].x + m0.y*k[0][0].y + m0.z*k[0][0].z + m0.w*k[0][0].w
                     + m1.x*k[0][1].x + m1.y*k[0][1].y + m1.z*k[0][1].z + m1.w*k[0][1].w;
            float s1 = m0.x*k[1][0].x + m0.y*k[1][0].y + m0.z*k[1][0].z + m0.w*k[1][0].w
                     + m1.x*k[1][1].x + m1.y*k[1][1].y + m1.z*k[1][1].z + m1.w*k[1][1].w;
            float s2 = m0.x*k[2][0].x + m0.y*k[2][0].y + m0.z*k[2][0].z + m0.w*k[2][0].w
                     + m1.x*k[2][1].x + m1.y*k[2][1].y + m1.z*k[2][1].z + m1.w*k[2][1].w;
            float s3 = m0.x*k[3][0].x + m0.y*k[3][0].y + m0.z*k[3][0].z + m0.w*k[3][0].w
                     + m1.x*k[3][1].x + m1.y*k[3][1].y + m1.z*k[3][1].z + m1.w*k[3][1].w;
            float nn = m0.x*m0.x + m0.y*m0.y + m0.z*m0.z + m0.w*m0.w
                     + m1.x*m1.x + m1.y*m1.y + m1.z*m1.z + m1.w*m1.w;
            s0 += __shfl_xor(s0, 1); s1 += __shfl_xor(s1, 1);
            s2 += __shfl_xor(s2, 1); s3 += __shfl_xor(s3, 1); nn += __shfl_xor(nn, 1);
            float p01 = (j & 1) ? s1 : s0;
            float p23 = (j & 1) ? s3 : s2;
            p01 += __shfl_xor(p01, 2); p23 += __shfl_xor(p23, 2); nn += __shfl_xor(nn, 2);
            float q = (j & 2) ? p23 : p01;
            q += __shfl_xor(q, 4);  nn += __shfl_xor(nn, 4);
            q += __shfl_xor(q, 8);  nn += __shfl_xor(nn, 8);
            if (j < 4) sim[((size_t)(b * 4 + j)) * N + n] = q / (sqrtf(nn) + EPSF);
        }
    }
}

// ---------------------------------------------------------------- address finalize
// 512 threads; pow result stored in pbuf, not recomputed. (R1/R3-proven version.)
__global__ __launch_bounds__(512) void addr_finalize(const float* __restrict__ sim,
        const float* __restrict__ prev_w, const float* __restrict__ par,
        float* __restrict__ w_out) {
    __shared__ float buf[N];    // 32KB
    __shared__ float pbuf[N];   // 32KB
    __shared__ float red[8];
    int bh = blockIdx.x;
    int t = threadIdx.x;
    const float* s = sim + (size_t)bh * N;
    const float* pw = prev_w + (size_t)bh * N;
    float beta = par[bh * 6 + 0], g = par[bh * 6 + 1];
    float s0 = par[bh * 6 + 2], s1 = par[bh * 6 + 3], s2 = par[bh * 6 + 4];
    float gamma = par[bh * 6 + 5];
    float mx = -INFINITY;
    for (int i = t; i < N; i += 512) {
        float e = beta * s[i];
        buf[i] = e;
        mx = fmaxf(mx, e);
    }
    #pragma unroll
    for (int m = 1; m < 64; m <<= 1) mx = fmaxf(mx, __shfl_xor(mx, m));
    if ((t & 63) == 0) red[t >> 6] = mx;
    __syncthreads();
    mx = red[0];
    #pragma unroll
    for (int kk = 1; kk < 8; kk++) mx = fmaxf(mx, red[kk]);
    float sum = 0.f;
    for (int i = t; i < N; i += 512) {
        float v = expf(buf[i] - mx);
        buf[i] = v;
        sum += v;
    }
    #pragma unroll
    for (int m = 1; m < 64; m <<= 1) sum += __shfl_xor(sum, m);
    __syncthreads();
    if ((t & 63) == 0) red[t >> 6] = sum;
    __syncthreads();
    sum = red[0] + red[1] + red[2] + red[3] + red[4] + red[5] + red[6] + red[7];
    float inv = 1.f / sum;
    for (int i = t; i < N; i += 512) buf[i] = g * (buf[i] * inv) + (1.f - g) * pw[i];
    __syncthreads();
    float psum = 0.f;
    for (int i = t; i < N; i += 512) {
        float wsv = s0 * buf[(i + N - 1) & (N - 1)] + s1 * buf[i] + s2 * buf[(i + 1) & (N - 1)];
        float pv = powf(wsv, gamma);
        pbuf[i] = pv;
        psum += pv;
    }
    #pragma unroll
    for (int m = 1; m < 64; m <<= 1) psum += __shfl_xor(psum, m);
    __syncthreads();
    if ((t & 63) == 0) red[t >> 6] = psum;
    __syncthreads();
    psum = red[0] + red[1] + red[2] + red[3] + red[4] + red[5] + red[6] + red[7];
    float rinv = 1.f / (psum + EPSF);
    for (int i = t; i < N; i += 512) w_out[(size_t)bh * N + i] = pbuf[i] * rinv;
}

// ---------------------------------------------------------------- memory update + read-head sim (fused)
// Grid-stride: 2048 blocks x 4 chunks; e/a/kr loaded ONCE per block (4x fewer scalar loads).
// w_w staged through LDS per chunk; packed reduce; NT stream both directions.
__global__ __launch_bounds__(256) void mem_update(const float* __restrict__ mem_in,
        const float* __restrict__ o_w, const float* __restrict__ w_w,
        const float* __restrict__ knr, float* __restrict__ mem_out,
        float* __restrict__ simr) {
    __shared__ float wlds[4][64];
    int t = threadIdx.x;
    int l = t & 31;
    int rg = t >> 5;
    int b = blockIdx.x >> 5;
    int grp = blockIdx.x & 31;
    f4 e[4], a[4], kr[4];
    #pragma unroll
    for (int h = 0; h < 4; h++) {
        const float* ob = o_w + b * 1560 + h * GDW;
        // offsets only 8B-aligned: scalar loads
        e[h].x = ob[134 + l * 4 + 0]; e[h].y = ob[134 + l * 4 + 1];
        e[h].z = ob[134 + l * 4 + 2]; e[h].w = ob[134 + l * 4 + 3];
        a[h].x = ob[262 + l * 4 + 0]; a[h].y = ob[262 + l * 4 + 1];
        a[h].z = ob[262 + l * 4 + 2]; a[h].w = ob[262 + l * 4 + 3];
        kr[h] = *(const f4*)(knr + (b * 4 + h) * 128 + l * 4);
    }
    for (int cc = 0; cc < 4; cc++) {
        int n0 = (grp * 4 + cc) * 64;
        __syncthreads();
        {
            int h = t >> 6, idx = t & 63;
            wlds[h][idx] = w_w[((size_t)(b * 4 + h)) * N + n0 + idx];
        }
        __syncthreads();
        #pragma unroll
        for (int it = 0; it < 8; it++) {
            int n = n0 + it * 8 + rg;
            size_t base = ((size_t)b * N + n) * D + l * 4;
            f4 m = ntload4(mem_in + base);
            #pragma unroll
            for (int h = 0; h < 4; h++) {
                float wv = wlds[h][it * 8 + rg];
                m.x = m.x * (1.f - wv * e[h].x) + wv * a[h].x;
                m.y = m.y * (1.f - wv * e[h].y) + wv * a[h].y;
                m.z = m.z * (1.f - wv * e[h].z) + wv * a[h].z;
                m.w = m.w * (1.f - wv * e[h].w) + wv * a[h].w;
            }
            ntstore4(mem_out + base, m);
            float s0 = m.x * kr[0].x + m.y * kr[0].y + m.z * kr[0].z + m.w * kr[0].w;
            float s1 = m.x * kr[1].x + m.y * kr[1].y + m.z * kr[1].z + m.w * kr[1].w;
            float s2 = m.x * kr[2].x + m.y * kr[2].y + m.z * kr[2].z + m.w * kr[2].w;
            float s3 = m.x * kr[3].x + m.y * kr[3].y + m.z * kr[3].z + m.w * kr[3].w;
            float nn = m.x * m.x + m.y * m.y + m.z * m.z + m.w * m.w;
            s0 += __shfl_xor(s0, 1); s1 += __shfl_xor(s1, 1);
            s2 += __shfl_xor(s2, 1); s3 += __shfl_xor(s3, 1); nn += __shfl_xor(nn, 1);
            float p01 = (l & 1) ? s1 : s0;
            float p23 = (l & 1) ? s3 : s2;
            p01 += __shfl_xor(p01, 2); p23 += __shfl_xor(p23, 2); nn += __shfl_xor(nn, 2);
            float q = (l & 2) ? p23 : p01;
            q += __shfl_xor(q, 4); nn += __shfl_xor(nn, 4);
            float z = (l & 4) ? nn : q;
            z += __shfl_xor(z, 8);
            z += __shfl_xor(z, 16);
            float nnv = __shfl_xor(z, 4);
            if (l < 4) simr[((size_t)(b * 4 + l)) * N + n] = z / (sqrtf(nnv) + EPSF);
        }
    }
}

// ---------------------------------------------------------------- read vector
// w_r staged through LDS; stream loop unrolled x4; mem read nontemporal.
__global__ __launch_bounds__(256) void read_vec(const float* __restrict__ mem,
        const float* __restrict__ w_r, float* __restrict__ r) {
    __shared__ float lds[8 * 512];
    __shared__ float wlds[4][512];
    int t = threadIdx.x;
    int l = t & 31;
    int rg = t >> 5;
    int b = blockIdx.x >> 4;
    int n0 = (blockIdx.x & 15) * 512;
    for (int i = t; i < 2048; i += 256) {
        int h = i >> 9, idx = i & 511;
        wlds[h][idx] = w_r[((size_t)(b * 4 + h)) * N + n0 + idx];
    }
    __syncthreads();
    f4 acc[4];
    #pragma unroll
    for (int h = 0; h < 4; h++) acc[h] = (f4){0.f, 0.f, 0.f, 0.f};
    #pragma unroll 4
    for (int it = 0; it < 64; it++) {
        int nl = it * 8 + rg;
        const f4 m = ntload4(mem + ((size_t)b * N + n0 + nl) * D + l * 4);
        #pragma unroll
        for (int h = 0; h < 4; h++) {
            float wv = wlds[h][nl];
            acc[h].x += wv * m.x;
            acc[h].y += wv * m.y;
            acc[h].z += wv * m.z;
            acc[h].w += wv * m.w;
        }
    }
    #pragma unroll
    for (int h = 0; h < 4; h++) *(f4*)(lds + rg * 512 + h * 128 + l * 4) = acc[h];
    __syncthreads();
    for (int o = t; o < 512; o += 256) {
        float sum = 0.f;
        #pragma unroll
        for (int g2 = 0; g2 < 8; g2++) sum += lds[g2 * 512 + o];
        atomicAdd(&r[b * 512 + o], sum);
    }
}

// ---------------------------------------------------------------- output
__global__ __launch_bounds__(64) void out_y(const float* __restrict__ h,
        const float* __restrict__ r, const float* __restrict__ W_out,
        const float* __restrict__ b_out, float* __restrict__ y) {
    int b = blockIdx.x >> 6;
    int j = blockIdx.x & 63;
    int l = threadIdx.x;
    float acc = 0.f;
    #pragma unroll
    for (int kk = 0; kk < 16; kk++) {
        int k = l + kk * 64;
        float x = (k < 512) ? h[b * 512 + k] : r[b * 512 + (k - 512)];
        acc = fmaf(W_out[j * 1024 + k], x, acc);
    }
    #pragma unroll
    for (int m = 1; m < 64; m <<= 1) acc += __shfl_xor(acc, m);
    if (l == 0) y[b * 64 + j] = tanhf(acc + b_out[j]);
}

extern "C" void kernel_launch(void* const* d_in, const int* in_sizes, int n_in,
                              void* d_out, int out_size, void* d_ws, size_t ws_size,
                              hipStream_t stream) {
    const float* x_input      = (const float*)d_in[0];
    const float* prev_y       = (const float*)d_in[1];
    const float* prev_read    = (const float*)d_in[2];
    const float* memory       = (const float*)d_in[3];
    const float* prev_w_read  = (const float*)d_in[4];
    const float* prev_w_write = (const float*)d_in[5];
    const float* h0           = (const float*)d_in[6];
    const float* c0           = (const float*)d_in[7];
    const float* W_ih         = (const float*)d_in[8];
    const float* W_hh         = (const float*)d_in[9];
    const float* b_ih         = (const float*)d_in[10];
    const float* b_hh         = (const float*)d_in[11];
    const float* W_rhead      = (const float*)d_in[12];
    const float* b_rhead      = (const float*)d_in[13];
    const float* W_whead      = (const float*)d_in[14];
    const float* b_whead      = (const float*)d_in[15];
    const float* W_out        = (const float*)d_in[16];
    const float* b_out        = (const float*)d_in[17];

    float* out = (float*)d_out;
    float* y_o   = out;                        // 4096
    float* mem_o = out + 4096;                 // 67108864
    float* h_o   = out + 4096 + 67108864;      // 32768
    float* c_o   = h_o + 32768;                // 32768
    float* wr_o  = c_o + 32768;                // 2097152
    float* ww_o  = wr_o + 2097152;             // 2097152

    float* ws     = (float*)d_ws;
    float* XT     = ws;                        // 73728
    float* HT     = XT + 73728;                // 32768
    float* gatesT = HT + 32768;                // 131072
    float* o_w    = gatesT + 131072;           // 99840  (64*1560)
    float* o_r    = o_w + 99840;               // 34304  (64*536)
    float* knw    = o_r + 34304;               // 32768
    float* knr    = knw + 32768;               // 32768
    float* pw     = knr + 32768;               // 1536
    float* prd    = pw + 1536;                 // 1536
    float* sim_w  = prd + 1536;                // 2097152
    float* sim_r  = sim_w + 2097152;           // 2097152
    float* r_ws   = sim_r + 2097152;           // 32768

    prep_xt<<<288, 256, 0, stream>>>(x_input, prev_y, prev_read, h0, XT);
    controller<<<128, 256, 0, stream>>>(XT, W_ih, W_hh, b_ih, b_hh, gatesT);
    lstm_cell<<<128, 256, 0, stream>>>(gatesT, c0, h_o, c_o, HT);
    head_proj<<<131, 256, 0, stream>>>(HT, W_whead, W_rhead, b_whead, b_rhead, o_w, o_r);
    head_params<<<512, 128, 0, stream>>>(o_w, o_r, knw, knr, pw, prd, r_ws);
    sim_write<<<2048, 256, 0, stream>>>(memory, knw, sim_w);
    addr_finalize<<<256, 512, 0, stream>>>(sim_w, prev_w_write, pw, ww_o);
    mem_update<<<2048, 256, 0, stream>>>(memory, o_w, ww_o, knr, mem_o, sim_r);
    addr_finalize<<<256, 512, 0, stream>>>(sim_r, prev_w_read, prd, wr_o);
    read_vec<<<1024, 256, 0, stream>>>(mem_o, wr_o, r_ws);
    out_y<<<4096, 64, 0, stream>>>(h_o, r_ws, W_out, b_out, y_o);
}

// Round 6
// 713.952 us; speedup vs baseline: 1.1685x; 1.0459x over previous
//
#include <hip/hip_runtime.h>
#include <math.h>

#define B 64
#define N 8192
#define D 128
#define H 512
#define NHEAD 4
#define GDW 390
#define GDR 134
#define KL 1152   /* 640 + 512 */
#define EPSF 1e-10f

typedef float f4 __attribute__((ext_vector_type(4)));

__device__ __forceinline__ float softplusf(float x) {
    return x > 20.f ? x : log1pf(expf(x));
}
__device__ __forceinline__ float sigmoidf(float x) {
    return 1.f / (1.f + expf(-x));
}
__device__ __forceinline__ f4 ntload4(const float* p) {
    return __builtin_nontemporal_load((const f4*)p);
}
__device__ __forceinline__ void ntstore4(float* p, f4 v) {
    __builtin_nontemporal_store(v, (f4*)p);
}

// ---------------------------------------------------------------- prep XT
__global__ void prep_xt(const float* __restrict__ x, const float* __restrict__ py,
                        const float* __restrict__ pr, const float* __restrict__ h0,
                        float* __restrict__ XT) {
    int idx = blockIdx.x * 256 + threadIdx.x;
    if (idx >= KL * B) return;
    int k = idx >> 6, b = idx & 63;
    float v;
    if (k < 64)       v = x[b * 64 + k];
    else if (k < 128) v = py[b * 64 + (k - 64)];
    else if (k < 640) v = pr[b * 512 + (k - 128)];
    else              v = h0[b * 512 + (k - 640)];
    XT[idx] = v;
}

// ---------------------------------------------------------------- controller GEMM
__global__ __launch_bounds__(256) void controller(const float* __restrict__ XT,
        const float* __restrict__ W_ih, const float* __restrict__ W_hh,
        const float* __restrict__ b_ih, const float* __restrict__ b_hh,
        float* __restrict__ gatesT) {
    __shared__ float xs[64 * 64];
    int tid = threadIdx.x;
    int lane = tid & 63;
    int wave = tid >> 6;
    int j0 = blockIdx.x * 16 + wave * 4;
    float acc[4] = {0.f, 0.f, 0.f, 0.f};
    for (int k0 = 0; k0 < KL; k0 += 64) {
        __syncthreads();
        #pragma unroll
        for (int i = 0; i < 16; i++) xs[tid + i * 256] = XT[k0 * 64 + tid + i * 256];
        __syncthreads();
        const float* wp[4];
        #pragma unroll
        for (int jj = 0; jj < 4; jj++) {
            int j = j0 + jj;
            wp[jj] = (k0 < 640) ? (W_ih + j * 640 + k0) : (W_hh + j * 512 + (k0 - 640));
        }
        #pragma unroll 4
        for (int k = 0; k < 64; k++) {
            float xv = xs[k * 64 + lane];
            #pragma unroll
            for (int jj = 0; jj < 4; jj++) acc[jj] = fmaf(wp[jj][k], xv, acc[jj]);
        }
    }
    #pragma unroll
    for (int jj = 0; jj < 4; jj++) {
        int j = j0 + jj;
        gatesT[j * 64 + lane] = acc[jj] + b_ih[j] + b_hh[j];
    }
}

// ---------------------------------------------------------------- LSTM cell
__global__ void lstm_cell(const float* __restrict__ gatesT, const float* __restrict__ c0,
                          float* __restrict__ h_out, float* __restrict__ c_out,
                          float* __restrict__ HT) {
    int tid = blockIdx.x * 256 + threadIdx.x;  // 32768
    int b = tid >> 9, u = tid & 511;
    float gi = gatesT[u * 64 + b];
    float gf = gatesT[(512 + u) * 64 + b];
    float gg = gatesT[(1024 + u) * 64 + b];
    float go = gatesT[(1536 + u) * 64 + b];
    float c = sigmoidf(gf) * c0[b * 512 + u] + sigmoidf(gi) * tanhf(gg);
    float h = sigmoidf(go) * tanhf(c);
    c_out[b * 512 + u] = c;
    h_out[b * 512 + u] = h;
    HT[u * 64 + b] = h;
}

// ---------------------------------------------------------------- head projections
__global__ __launch_bounds__(256) void head_proj(const float* __restrict__ HT,
        const float* __restrict__ W_w, const float* __restrict__ W_r,
        const float* __restrict__ b_w, const float* __restrict__ b_r,
        float* __restrict__ o_w, float* __restrict__ o_r) {
    __shared__ float xs[64 * 64];
    int tid = threadIdx.x;
    int lane = tid & 63;
    int wave = tid >> 6;
    int j0 = blockIdx.x * 16 + wave * 4;
    float acc[4] = {0.f, 0.f, 0.f, 0.f};
    const float* wp[4];
    #pragma unroll
    for (int jj = 0; jj < 4; jj++) {
        int j = j0 + jj;
        wp[jj] = (j < 1560) ? (W_w + j * 512) : (W_r + (j - 1560) * 512);
    }
    for (int k0 = 0; k0 < 512; k0 += 64) {
        __syncthreads();
        #pragma unroll
        for (int i = 0; i < 16; i++) xs[tid + i * 256] = HT[k0 * 64 + tid + i * 256];
        __syncthreads();
        #pragma unroll 4
        for (int k = 0; k < 64; k++) {
            float xv = xs[k * 64 + lane];
            #pragma unroll
            for (int jj = 0; jj < 4; jj++) acc[jj] = fmaf(wp[jj][k0 + k], xv, acc[jj]);
        }
    }
    #pragma unroll
    for (int jj = 0; jj < 4; jj++) {
        int j = j0 + jj;
        if (j < 1560) o_w[lane * 1560 + j] = acc[jj] + b_w[j];
        else          o_r[lane * 536 + (j - 1560)] = acc[jj] + b_r[j - 1560];
    }
}

// ---------------------------------------------------------------- head params (+ zero r workspace)
__global__ __launch_bounds__(128) void head_params(const float* __restrict__ o_w,
        const float* __restrict__ o_r, float* __restrict__ knw, float* __restrict__ knr,
        float* __restrict__ pw, float* __restrict__ prd, float* __restrict__ rzero) {
    __shared__ float red[2];
    int id = blockIdx.x;
    if (id < 256) rzero[id * 128 + threadIdx.x] = 0.f;   // fused zero of r workspace (32768)
    bool isw = id < 256;
    int bh = isw ? id : id - 256;
    const float* o = isw ? (o_w + (bh >> 2) * 1560 + (bh & 3) * GDW)
                         : (o_r + (bh >> 2) * 536 + (bh & 3) * GDR);
    float* kn = (isw ? knw : knr) + bh * 128;
    float* pp = (isw ? pw : prd) + bh * 6;
    int t = threadIdx.x;
    float kv = o[t];
    float ss = kv * kv;
    #pragma unroll
    for (int m = 1; m < 64; m <<= 1) ss += __shfl_xor(ss, m);
    if ((t & 63) == 0) red[t >> 6] = ss;
    __syncthreads();
    float norm = sqrtf(red[0] + red[1]);
    kn[t] = kv / (norm + EPSF);
    if (t == 0) {
        float beta = softplusf(o[128]);
        float g = sigmoidf(o[129]);
        float s0 = softplusf(o[130]), s1 = softplusf(o[131]), s2 = softplusf(o[132]);
        float mx = fmaxf(s0, fmaxf(s1, s2));
        float e0 = expf(s0 - mx), e1 = expf(s1 - mx), e2 = expf(s2 - mx);
        float inv = 1.f / (e0 + e1 + e2);
        float gamma = 1.f + softplusf(o[133]);
        pp[0] = beta; pp[1] = g; pp[2] = e0 * inv; pp[3] = e1 * inv; pp[4] = e2 * inv; pp[5] = gamma;
    }
}

// ---------------------------------------------------------------- sim (write heads)
// R3-proven: 8192 blocks, 64 rows each, 16 lanes/row, packed reduce, NT mem reads.
__global__ __launch_bounds__(256) void sim_write(const float* __restrict__ mem,
        const float* __restrict__ knw, float* __restrict__ sim) {
    int t = threadIdx.x;
    int lane = t & 63;
    int wv = t >> 6;
    int j = lane & 15;
    int u = lane >> 4;
    int b = blockIdx.x >> 7;
    int nb = (blockIdx.x & 127) * 64 + wv * 16 + u;
    f4 k[4][2];
    #pragma unroll
    for (int h = 0; h < 4; h++) {
        #pragma unroll
        for (int s = 0; s < 2; s++)
            k[h][s] = *(const f4*)(knw + (b * 4 + h) * 128 + s * 64 + j * 4);
    }
    #pragma unroll
    for (int it = 0; it < 4; it++) {
        int n = nb + it * 4;
        size_t base = ((size_t)b * N + n) * D + j * 4;
        const f4 m0 = ntload4(mem + base);
        const f4 m1 = ntload4(mem + base + 64);
        float s0 = m0.x*k[0][0].x + m0.y*k[0][0].y + m0.z*k[0][0].z + m0.w*k[0][0].w
                 + m1.x*k[0][1].x + m1.y*k[0][1].y + m1.z*k[0][1].z + m1.w*k[0][1].w;
        float s1 = m0.x*k[1][0].x + m0.y*k[1][0].y + m0.z*k[1][0].z + m0.w*k[1][0].w
                 + m1.x*k[1][1].x + m1.y*k[1][1].y + m1.z*k[1][1].z + m1.w*k[1][1].w;
        float s2 = m0.x*k[2][0].x + m0.y*k[2][0].y + m0.z*k[2][0].z + m0.w*k[2][0].w
                 + m1.x*k[2][1].x + m1.y*k[2][1].y + m1.z*k[2][1].z + m1.w*k[2][1].w;
        float s3 = m0.x*k[3][0].x + m0.y*k[3][0].y + m0.z*k[3][0].z + m0.w*k[3][0].w
                 + m1.x*k[3][1].x + m1.y*k[3][1].y + m1.z*k[3][1].z + m1.w*k[3][1].w;
        float nn = m0.x*m0.x + m0.y*m0.y + m0.z*m0.z + m0.w*m0.w
                 + m1.x*m1.x + m1.y*m1.y + m1.z*m1.z + m1.w*m1.w;
        s0 += __shfl_xor(s0, 1); s1 += __shfl_xor(s1, 1);
        s2 += __shfl_xor(s2, 1); s3 += __shfl_xor(s3, 1); nn += __shfl_xor(nn, 1);
        float p01 = (j & 1) ? s1 : s0;
        float p23 = (j & 1) ? s3 : s2;
        p01 += __shfl_xor(p01, 2); p23 += __shfl_xor(p23, 2); nn += __shfl_xor(nn, 2);
        float q = (j & 2) ? p23 : p01;
        q += __shfl_xor(q, 4);  nn += __shfl_xor(nn, 4);
        q += __shfl_xor(q, 8);  nn += __shfl_xor(nn, 8);
        if (j < 4) sim[((size_t)(b * 4 + j)) * N + n] = q / (sqrtf(nn) + EPSF);
    }
}

// ---------------------------------------------------------------- address finalize
// 512 threads; f4-vectorized global streams; 4 barriers via disjoint red slots;
// pow stored in pbuf. Arithmetic identical to prior rounds.
__global__ __launch_bounds__(512) void addr_finalize(const float* __restrict__ sim,
        const float* __restrict__ prev_w, const float* __restrict__ par,
        float* __restrict__ w_out) {
    __shared__ float buf[N];    // 32KB
    __shared__ float pbuf[N];   // 32KB
    __shared__ float red[24];   // [0..7] mx, [8..15] sum, [16..23] psum
    int bh = blockIdx.x;
    int t = threadIdx.x;
    int wv = t >> 6;
    const f4* s4 = (const f4*)(sim + (size_t)bh * N);
    const f4* pw4 = (const f4*)(prev_w + (size_t)bh * N);
    f4* out4 = (f4*)(w_out + (size_t)bh * N);
    float beta = par[bh * 6 + 0], g = par[bh * 6 + 1];
    float s0 = par[bh * 6 + 2], s1 = par[bh * 6 + 3], s2 = par[bh * 6 + 4];
    float gamma = par[bh * 6 + 5];
    // P1: e = beta*sim (f4 loads), track max
    float mx = -INFINITY;
    #pragma unroll
    for (int c = t; c < N / 4; c += 512) {
        f4 v = s4[c];
        v.x *= beta; v.y *= beta; v.z *= beta; v.w *= beta;
        *(f4*)(buf + c * 4) = v;
        mx = fmaxf(mx, fmaxf(fmaxf(v.x, v.y), fmaxf(v.z, v.w)));
    }
    #pragma unroll
    for (int m = 1; m < 64; m <<= 1) mx = fmaxf(mx, __shfl_xor(mx, m));
    if ((t & 63) == 0) red[wv] = mx;
    __syncthreads();                                   // B1: mx ready + P1 buf writes visible
    mx = red[0];
    #pragma unroll
    for (int kk = 1; kk < 8; kk++) mx = fmaxf(mx, red[kk]);
    // P2: exp + sum (same order as before: i = t step 512)
    float sum = 0.f;
    for (int i = t; i < N; i += 512) {
        float v = expf(buf[i] - mx);
        buf[i] = v;
        sum += v;
    }
    #pragma unroll
    for (int m = 1; m < 64; m <<= 1) sum += __shfl_xor(sum, m);
    if ((t & 63) == 0) red[8 + wv] = sum;
    __syncthreads();                                   // B2: sum ready + P2 buf writes visible
    sum = red[8] + red[9] + red[10] + red[11] + red[12] + red[13] + red[14] + red[15];
    float inv = 1.f / sum;
    // P3: wg = g*wc + (1-g)*prev_w  (f4 loads of prev_w)
    #pragma unroll
    for (int c = t; c < N / 4; c += 512) {
        f4 p = pw4[c];
        f4 w;
        w.x = g * (buf[c * 4 + 0] * inv) + (1.f - g) * p.x;
        w.y = g * (buf[c * 4 + 1] * inv) + (1.f - g) * p.y;
        w.z = g * (buf[c * 4 + 2] * inv) + (1.f - g) * p.z;
        w.w = g * (buf[c * 4 + 3] * inv) + (1.f - g) * p.w;
        *(f4*)(buf + c * 4) = w;
    }
    __syncthreads();                                   // B3: wg complete (shift reads neighbors)
    // P4: shift + pow, store pow, sum (same order as before)
    float psum = 0.f;
    for (int i = t; i < N; i += 512) {
        float wsv = s0 * buf[(i + N - 1) & (N - 1)] + s1 * buf[i] + s2 * buf[(i + 1) & (N - 1)];
        float pv = powf(wsv, gamma);
        pbuf[i] = pv;
        psum += pv;
    }
    #pragma unroll
    for (int m = 1; m < 64; m <<= 1) psum += __shfl_xor(psum, m);
    if ((t & 63) == 0) red[16 + wv] = psum;
    __syncthreads();                                   // B4: psum ready + pbuf visible
    psum = red[16] + red[17] + red[18] + red[19] + red[20] + red[21] + red[22] + red[23];
    float rinv = 1.f / (psum + EPSF);
    // P5: normalized write (f4 stores)
    #pragma unroll
    for (int c = t; c < N / 4; c += 512) {
        f4 o;
        o.x = pbuf[c * 4 + 0] * rinv;
        o.y = pbuf[c * 4 + 1] * rinv;
        o.z = pbuf[c * 4 + 2] * rinv;
        o.w = pbuf[c * 4 + 3] * rinv;
        out4[c] = o;
    }
}

// ---------------------------------------------------------------- memory update + read-head sim (fused)
// R3-proven: 8192 blocks, 64 rows each; w_w via LDS; unrolled; NT both directions.
__global__ __launch_bounds__(256) void mem_update(const float* __restrict__ mem_in,
        const float* __restrict__ o_w, const float* __restrict__ w_w,
        const float* __restrict__ knr, float* __restrict__ mem_out,
        float* __restrict__ simr) {
    __shared__ float wlds[4][64];
    int t = threadIdx.x;
    int l = t & 31;
    int rg = t >> 5;
    int b = blockIdx.x >> 7;
    int n0 = (blockIdx.x & 127) * 64;
    {
        int h = t >> 6, idx = t & 63;
        wlds[h][idx] = w_w[((size_t)(b * 4 + h)) * N + n0 + idx];
    }
    f4 e[4], a[4], kr[4];
    #pragma unroll
    for (int h = 0; h < 4; h++) {
        const float* ob = o_w + b * 1560 + h * GDW;
        // offsets only 8B-aligned: scalar loads
        e[h].x = ob[134 + l * 4 + 0]; e[h].y = ob[134 + l * 4 + 1];
        e[h].z = ob[134 + l * 4 + 2]; e[h].w = ob[134 + l * 4 + 3];
        a[h].x = ob[262 + l * 4 + 0]; a[h].y = ob[262 + l * 4 + 1];
        a[h].z = ob[262 + l * 4 + 2]; a[h].w = ob[262 + l * 4 + 3];
        kr[h] = *(const f4*)(knr + (b * 4 + h) * 128 + l * 4);
    }
    __syncthreads();
    #pragma unroll
    for (int it = 0; it < 8; it++) {
        int n = n0 + it * 8 + rg;
        size_t base = ((size_t)b * N + n) * D + l * 4;
        f4 m = ntload4(mem_in + base);
        #pragma unroll
        for (int h = 0; h < 4; h++) {
            float wv = wlds[h][it * 8 + rg];
            m.x = m.x * (1.f - wv * e[h].x) + wv * a[h].x;
            m.y = m.y * (1.f - wv * e[h].y) + wv * a[h].y;
            m.z = m.z * (1.f - wv * e[h].z) + wv * a[h].z;
            m.w = m.w * (1.f - wv * e[h].w) + wv * a[h].w;
        }
        ntstore4(mem_out + base, m);
        float s0 = m.x * kr[0].x + m.y * kr[0].y + m.z * kr[0].z + m.w * kr[0].w;
        float s1 = m.x * kr[1].x + m.y * kr[1].y + m.z * kr[1].z + m.w * kr[1].w;
        float s2 = m.x * kr[2].x + m.y * kr[2].y + m.z * kr[2].z + m.w * kr[2].w;
        float s3 = m.x * kr[3].x + m.y * kr[3].y + m.z * kr[3].z + m.w * kr[3].w;
        float nn = m.x * m.x + m.y * m.y + m.z * m.z + m.w * m.w;
        s0 += __shfl_xor(s0, 1); s1 += __shfl_xor(s1, 1);
        s2 += __shfl_xor(s2, 1); s3 += __shfl_xor(s3, 1); nn += __shfl_xor(nn, 1);
        float p01 = (l & 1) ? s1 : s0;
        float p23 = (l & 1) ? s3 : s2;
        p01 += __shfl_xor(p01, 2); p23 += __shfl_xor(p23, 2); nn += __shfl_xor(nn, 2);
        float q = (l & 2) ? p23 : p01;
        q += __shfl_xor(q, 4); nn += __shfl_xor(nn, 4);
        float z = (l & 4) ? nn : q;
        z += __shfl_xor(z, 8);
        z += __shfl_xor(z, 16);
        float nnv = __shfl_xor(z, 4);
        if (l < 4) simr[((size_t)(b * 4 + l)) * N + n] = z / (sqrtf(nnv) + EPSF);
    }
}

// ---------------------------------------------------------------- read vector
// w_r staged through LDS; stream loop unrolled x4; mem read nontemporal.
__global__ __launch_bounds__(256) void read_vec(const float* __restrict__ mem,
        const float* __restrict__ w_r, float* __restrict__ r) {
    __shared__ float lds[8 * 512];
    __shared__ float wlds[4][512];
    int t = threadIdx.x;
    int l = t & 31;
    int rg = t >> 5;
    int b = blockIdx.x >> 4;
    int n0 = (blockIdx.x & 15) * 512;
    for (int i = t; i < 2048; i += 256) {
        int h = i >> 9, idx = i & 511;
        wlds[h][idx] = w_r[((size_t)(b * 4 + h)) * N + n0 + idx];
    }
    __syncthreads();
    f4 acc[4];
    #pragma unroll
    for (int h = 0; h < 4; h++) acc[h] = (f4){0.f, 0.f, 0.f, 0.f};
    #pragma unroll 4
    for (int it = 0; it < 64; it++) {
        int nl = it * 8 + rg;
        const f4 m = ntload4(mem + ((size_t)b * N + n0 + nl) * D + l * 4);
        #pragma unroll
        for (int h = 0; h < 4; h++) {
            float wv = wlds[h][nl];
            acc[h].x += wv * m.x;
            acc[h].y += wv * m.y;
            acc[h].z += wv * m.z;
            acc[h].w += wv * m.w;
        }
    }
    #pragma unroll
    for (int h = 0; h < 4; h++) *(f4*)(lds + rg * 512 + h * 128 + l * 4) = acc[h];
    __syncthreads();
    for (int o = t; o < 512; o += 256) {
        float sum = 0.f;
        #pragma unroll
        for (int g2 = 0; g2 < 8; g2++) sum += lds[g2 * 512 + o];
        atomicAdd(&r[b * 512 + o], sum);
    }
}

// ---------------------------------------------------------------- output
__global__ __launch_bounds__(64) void out_y(const float* __restrict__ h,
        const float* __restrict__ r, const float* __restrict__ W_out,
        const float* __restrict__ b_out, float* __restrict__ y) {
    int b = blockIdx.x >> 6;
    int j = blockIdx.x & 63;
    int l = threadIdx.x;
    float acc = 0.f;
    #pragma unroll
    for (int kk = 0; kk < 16; kk++) {
        int k = l + kk * 64;
        float x = (k < 512) ? h[b * 512 + k] : r[b * 512 + (k - 512)];
        acc = fmaf(W_out[j * 1024 + k], x, acc);
    }
    #pragma unroll
    for (int m = 1; m < 64; m <<= 1) acc += __shfl_xor(acc, m);
    if (l == 0) y[b * 64 + j] = tanhf(acc + b_out[j]);
}

extern "C" void kernel_launch(void* const* d_in, const int* in_sizes, int n_in,
                              void* d_out, int out_size, void* d_ws, size_t ws_size,
                              hipStream_t stream) {
    const float* x_input      = (const float*)d_in[0];
    const float* prev_y       = (const float*)d_in[1];
    const float* prev_read    = (const float*)d_in[2];
    const float* memory       = (const float*)d_in[3];
    const float* prev_w_read  = (const float*)d_in[4];
    const float* prev_w_write = (const float*)d_in[5];
    const float* h0           = (const float*)d_in[6];
    const float* c0           = (const float*)d_in[7];
    const float* W_ih         = (const float*)d_in[8];
    const float* W_hh         = (const float*)d_in[9];
    const float* b_ih         = (const float*)d_in[10];
    const float* b_hh         = (const float*)d_in[11];
    const float* W_rhead      = (const float*)d_in[12];
    const float* b_rhead      = (const float*)d_in[13];
    const float* W_whead      = (const float*)d_in[14];
    const float* b_whead      = (const float*)d_in[15];
    const float* W_out        = (const float*)d_in[16];
    const float* b_out        = (const float*)d_in[17];

    float* out = (float*)d_out;
    float* y_o   = out;                        // 4096
    float* mem_o = out + 4096;                 // 67108864
    float* h_o   = out + 4096 + 67108864;      // 32768
    float* c_o   = h_o + 32768;                // 32768
    float* wr_o  = c_o + 32768;                // 2097152
    float* ww_o  = wr_o + 2097152;             // 2097152

    float* ws     = (float*)d_ws;
    float* XT     = ws;                        // 73728
    float* HT     = XT + 73728;                // 32768
    float* gatesT = HT + 32768;                // 131072
    float* o_w    = gatesT + 131072;           // 99840  (64*1560)
    float* o_r    = o_w + 99840;               // 34304  (64*536)
    float* knw    = o_r + 34304;               // 32768
    float* knr    = knw + 32768;               // 32768
    float* pw     = knr + 32768;               // 1536
    float* prd    = pw + 1536;                 // 1536
    float* sim_w  = prd + 1536;                // 2097152
    float* sim_r  = sim_w + 2097152;           // 2097152
    float* r_ws   = sim_r + 2097152;           // 32768

    prep_xt<<<288, 256, 0, stream>>>(x_input, prev_y, prev_read, h0, XT);
    controller<<<128, 256, 0, stream>>>(XT, W_ih, W_hh, b_ih, b_hh, gatesT);
    lstm_cell<<<128, 256, 0, stream>>>(gatesT, c0, h_o, c_o, HT);
    head_proj<<<131, 256, 0, stream>>>(HT, W_whead, W_rhead, b_whead, b_rhead, o_w, o_r);
    head_params<<<512, 128, 0, stream>>>(o_w, o_r, knw, knr, pw, prd, r_ws);
    sim_write<<<8192, 256, 0, stream>>>(memory, knw, sim_w);
    addr_finalize<<<256, 512, 0, stream>>>(sim_w, prev_w_write, pw, ww_o);
    mem_update<<<8192, 256, 0, stream>>>(memory, o_w, ww_o, knr, mem_o, sim_r);
    addr_finalize<<<256, 512, 0, stream>>>(sim_r, prev_w_read, prd, wr_o);
    read_vec<<<1024, 256, 0, stream>>>(mem_o, wr_o, r_ws);
    out_y<<<4096, 64, 0, stream>>>(h_o, r_ws, W_out, b_out, y_o);
}